// Round 3
// baseline (169.932 us; speedup 1.0000x reference)
//
#include <hip/hip_runtime.h>
#include <hip/hip_bf16.h>

// Problem constants
#define N_PAIRS   64000
#define N_ATOMS   16000
#define N_FEAT    8
#define N_HIDDEN  100
// Padded dims
#define KP        128     // K (=100) padded to 128 for 4x mfma 16x16x32
#define SU        912     // U row stride: 57 n-tiles * 16 (covers 900 used cols)
#define MAX_DEG   64      // bucket capacity per src (Poisson(4): P(>=64) ~ 1e-56)

typedef __attribute__((ext_vector_type(8))) short bf16x8_t;   // 8 bf16 = 4 VGPRs
typedef __attribute__((ext_vector_type(4))) float f32x4_t;

// ---- prep: atom_features fp32 (16000x100) -> bf16 (16000x128, zero-padded K)
//      also zero-inits deg[] (folded in to save a dispatch)
__global__ __launch_bounds__(256) void prep_afb(const float* __restrict__ af,
                                                __hip_bfloat16* __restrict__ afb,
                                                int* __restrict__ deg) {
    int id  = blockIdx.x * 256 + threadIdx.x;      // < 16000*128
    if (id < N_ATOMS) deg[id] = 0;
    int row = id >> 7;
    int k   = id & 127;
    float v = (k < N_HIDDEN) ? af[row * N_HIDDEN + k] : 0.f;
    afb[id] = __float2bfloat16(v);
}

// ---- prep: Wt[c][k] with c = f*100+i (c<800), bias block c=800..899, zero pad
__global__ __launch_bounds__(256) void prep_wtb(const float* __restrict__ W,
                                                const float* __restrict__ b,
                                                __hip_bfloat16* __restrict__ wtb) {
    int id = blockIdx.x * 256 + threadIdx.x;       // < 912*128
    int c  = id >> 7;
    int k  = id & 127;
    float v = 0.f;
    if (k < N_HIDDEN) {
        if (c < N_FEAT * N_HIDDEN) {
            int f = c / N_HIDDEN;
            int i = c - f * N_HIDDEN;
            v = W[f * (N_HIDDEN * N_HIDDEN) + i * N_HIDDEN + k];
        } else if (c < (N_FEAT + 1) * N_HIDDEN) {
            int i = c - N_FEAT * N_HIDDEN;
            v = b[i * N_HIDDEN + k];
        }
    }
    wtb[id] = __float2bfloat16(v);
}

// ---- GEMM: U[a][c] = sum_k afb[a][k] * wtb[c][k], bf16 MFMA, U stored bf16
__global__ __launch_bounds__(256) void gemm_u(const __hip_bfloat16* __restrict__ afb,
                                              const __hip_bfloat16* __restrict__ wtb,
                                              __hip_bfloat16* __restrict__ u) {
    int wave = threadIdx.x >> 6;
    int lane = threadIdx.x & 63;
    int quad = lane >> 4;
    int l15  = lane & 15;
    int m0   = (blockIdx.x * 4 + wave) * 16;       // row tile base, < 16000

    const __hip_bfloat16* ap = afb + (m0 + l15) * KP + quad * 8;
    bf16x8_t a0 = *(const bf16x8_t*)(ap);
    bf16x8_t a1 = *(const bf16x8_t*)(ap + 32);
    bf16x8_t a2 = *(const bf16x8_t*)(ap + 64);
    bf16x8_t a3 = *(const bf16x8_t*)(ap + 96);

    int nt0 = blockIdx.y * 19;
    for (int nt = nt0; nt < nt0 + 19; ++nt) {
        int c = nt * 16 + l15;
        const __hip_bfloat16* bp = wtb + c * KP + quad * 8;
        bf16x8_t b0 = *(const bf16x8_t*)(bp);
        bf16x8_t b1 = *(const bf16x8_t*)(bp + 32);
        bf16x8_t b2 = *(const bf16x8_t*)(bp + 64);
        bf16x8_t b3 = *(const bf16x8_t*)(bp + 96);
        f32x4_t acc = {0.f, 0.f, 0.f, 0.f};
        acc = __builtin_amdgcn_mfma_f32_16x16x32_bf16(a0, b0, acc, 0, 0, 0);
        acc = __builtin_amdgcn_mfma_f32_16x16x32_bf16(a1, b1, acc, 0, 0, 0);
        acc = __builtin_amdgcn_mfma_f32_16x16x32_bf16(a2, b2, acc, 0, 0, 0);
        acc = __builtin_amdgcn_mfma_f32_16x16x32_bf16(a3, b3, acc, 0, 0, 0);
#pragma unroll
        for (int r = 0; r < 4; ++r) {
            int rr = m0 + quad * 4 + r;
            u[rr * SU + c] = __float2bfloat16(acc[r]);
        }
    }
}

// ---- bucket edges by SRC atom; pack (edge_id << 14) | dest (e<2^17, dest<2^14)
__global__ __launch_bounds__(256) void hist_bucket(const int* __restrict__ a2p,
                                                   int* __restrict__ deg,
                                                   unsigned* __restrict__ bucket) {
    int e = blockIdx.x * 256 + threadIdx.x;
    if (e >= N_PAIRS) return;
    int dest = a2p[e * 2];
    int src  = a2p[e * 2 + 1];
    int slot = atomicAdd(&deg[src], 1);
    if (slot < MAX_DEG)
        bucket[src * MAX_DEG + slot] = ((unsigned)e << 14) | (unsigned)dest;
}

// ---- spread: one wave per SRC atom. U[src] read ONCE (coalesced), staged to
//      LDS as fp32; per edge: msg from LDS + fp32 atomicAdd scatter to out[dest].
__global__ __launch_bounds__(256) void spread_kernel(const float* __restrict__ pf,
                                                     const __hip_bfloat16* __restrict__ u,
                                                     const int* __restrict__ deg,
                                                     const unsigned* __restrict__ bucket,
                                                     float* __restrict__ out) {
    __shared__ float lds[4][904];
    int wv   = threadIdx.x >> 6;
    int lane = threadIdx.x & 63;
    int s    = blockIdx.x * 4 + wv;                // src atom, < 16000
    float* row = lds[wv];

    // stage U[s] (900 cols used, 912 stored) into LDS as fp32; 2 coalesced b128 loads
    const unsigned short* ur = (const unsigned short*)(u + (size_t)s * SU);
    {
        ushort4 c0a = *(const ushort4*)(ur + 8 * lane);
        ushort4 c0b = *(const ushort4*)(ur + 8 * lane + 4);
        float4 f0 = {__uint_as_float((unsigned)c0a.x << 16),
                     __uint_as_float((unsigned)c0a.y << 16),
                     __uint_as_float((unsigned)c0a.z << 16),
                     __uint_as_float((unsigned)c0a.w << 16)};
        float4 f1 = {__uint_as_float((unsigned)c0b.x << 16),
                     __uint_as_float((unsigned)c0b.y << 16),
                     __uint_as_float((unsigned)c0b.z << 16),
                     __uint_as_float((unsigned)c0b.w << 16)};
        *(float4*)(&row[8 * lane])     = f0;
        *(float4*)(&row[8 * lane + 4]) = f1;
        if (lane < 49) {                           // cols 512..903
            ushort4 c1a = *(const ushort4*)(ur + 512 + 8 * lane);
            ushort4 c1b = *(const ushort4*)(ur + 512 + 8 * lane + 4);
            float4 g0 = {__uint_as_float((unsigned)c1a.x << 16),
                         __uint_as_float((unsigned)c1a.y << 16),
                         __uint_as_float((unsigned)c1a.z << 16),
                         __uint_as_float((unsigned)c1a.w << 16)};
            float4 g1 = {__uint_as_float((unsigned)c1b.x << 16),
                         __uint_as_float((unsigned)c1b.y << 16),
                         __uint_as_float((unsigned)c1b.z << 16),
                         __uint_as_float((unsigned)c1b.w << 16)};
            *(float4*)(&row[512 + 8 * lane])     = g0;
            *(float4*)(&row[512 + 8 * lane + 4]) = g1;
        }
    }
    __syncthreads();                               // staging visible (also intra-wave)

    int n = deg[s];                                // wave-uniform
    if (n > MAX_DEG) n = MAX_DEG;

    for (int t = 0; t < n; ++t) {
        unsigned pk = bucket[s * MAX_DEG + t];     // wave-uniform load
        int e    = (int)(pk >> 14);
        int dest = (int)(pk & 16383u);
        const float* pfe = pf + e * N_FEAT;
        float4 p0 = *(const float4*)(pfe);         // uniform -> broadcast
        float4 p1 = *(const float4*)(pfe + 4);
        if (lane < 50) {
            int i = 2 * lane;
            float a0 = row[800 + i];               // bias block of U[src]
            float a1 = row[800 + i + 1];
            float pv[8] = {p0.x, p0.y, p0.z, p0.w, p1.x, p1.y, p1.z, p1.w};
#pragma unroll
            for (int f = 0; f < N_FEAT; ++f) {
                a0 += pv[f] * row[f * N_HIDDEN + i];
                a1 += pv[f] * row[f * N_HIDDEN + i + 1];
            }
            atomicAdd(&out[dest * N_HIDDEN + i],     a0);
            atomicAdd(&out[dest * N_HIDDEN + i + 1], a1);
        }
    }
}

extern "C" void kernel_launch(void* const* d_in, const int* in_sizes, int n_in,
                              void* d_out, int out_size, void* d_ws, size_t ws_size,
                              hipStream_t stream) {
    const float* pf  = (const float*)d_in[0];   // (64000, 8)
    const float* af  = (const float*)d_in[1];   // (16000, 100)
    const int*   a2p = (const int*)d_in[2];     // (64000, 2)
    const float* W   = (const float*)d_in[3];   // (8, 10000)
    const float* b   = (const float*)d_in[4];   // (10000,)
    float* out = (float*)d_out;                 // (16000, 100) fp32

    char* ws = (char*)d_ws;
    __hip_bfloat16* afb = (__hip_bfloat16*)ws;                        // 4,096,000 B
    __hip_bfloat16* wtb = (__hip_bfloat16*)(ws + 4096000);            //   233,472 B
    __hip_bfloat16* u   = (__hip_bfloat16*)(ws + 4096000 + 233472);   // 29,184,000 B
    int* deg        = (int*)(ws + 4096000 + 233472 + 29184000);       //    64,000 B
    unsigned* bucket = (unsigned*)(ws + 4096000 + 233472 + 29184000 + 64000); // 4,096,000 B

    hipMemsetAsync(out, 0, (size_t)out_size * sizeof(float), stream);
    prep_afb<<<(N_ATOMS * KP) / 256, 256, 0, stream>>>(af, afb, deg);
    prep_wtb<<<(SU * KP) / 256, 256, 0, stream>>>(W, b, wtb);
    gemm_u<<<dim3(N_ATOMS / 64, 3), 256, 0, stream>>>(afb, wtb, u);
    hist_bucket<<<(N_PAIRS + 255) / 256, 256, 0, stream>>>(a2p, deg, bucket);
    spread_kernel<<<N_ATOMS / 4, 256, 0, stream>>>(pf, u, deg, bucket, out);
}

// Round 4
// 133.652 us; speedup vs baseline: 1.2714x; 1.2714x over previous
//
#include <hip/hip_runtime.h>
#include <hip/hip_bf16.h>

// Problem constants
#define N_PAIRS   64000
#define N_ATOMS   16000
#define N_FEAT    8
#define N_HIDDEN  100
// Padded dims
#define KP        128     // K (=100) padded to 128 for 4x mfma 16x16x32
#define SU        912     // U row stride: 57 n-tiles * 16 (covers 900 used cols)
#define MAX_DEG   64      // bucket capacity per dest (Poisson(4): P(>=64) ~ 1e-56)

typedef __attribute__((ext_vector_type(8))) short bf16x8_t;   // 8 bf16 = 4 VGPRs
typedef __attribute__((ext_vector_type(4))) float f32x4_t;

#define N1_SETUP (N_ATOMS * KP)   // 2,048,000 afb elements
#define N2_SETUP (SU * KP)        //   116,736 wtb elements

// ---- setup: afb (bf16, K-padded) + wtb (bf16 W^T with bias block), one kernel
__global__ __launch_bounds__(256) void setup_kernel(const float* __restrict__ af,
                                                    const float* __restrict__ W,
                                                    const float* __restrict__ b,
                                                    __hip_bfloat16* __restrict__ afb,
                                                    __hip_bfloat16* __restrict__ wtb) {
    int id = blockIdx.x * 256 + threadIdx.x;
    if (id < N1_SETUP) {
        int row = id >> 7;
        int k   = id & 127;
        float v = (k < N_HIDDEN) ? af[row * N_HIDDEN + k] : 0.f;
        afb[id] = __float2bfloat16(v);
    } else {
        int id2 = id - N1_SETUP;       // < 116,736
        int c  = id2 >> 7;
        int k  = id2 & 127;
        float v = 0.f;
        if (k < N_HIDDEN) {
            if (c < N_FEAT * N_HIDDEN) {
                int f = c / N_HIDDEN;
                int i = c - f * N_HIDDEN;
                v = W[f * (N_HIDDEN * N_HIDDEN) + i * N_HIDDEN + k];
            } else if (c < (N_FEAT + 1) * N_HIDDEN) {
                int i = c - N_FEAT * N_HIDDEN;
                v = b[i * N_HIDDEN + k];
            }
        }
        wtb[id2] = __float2bfloat16(v);
    }
}

// ---- GEMM: U[a][c] = sum_k afb[a][k] * wtb[c][k]; grid (250, 8): wave = one
//      16-row m-tile, 7 n-tiles (y==7 takes 8) -> 8000 waves, full occupancy
__global__ __launch_bounds__(256) void gemm_u(const __hip_bfloat16* __restrict__ afb,
                                              const __hip_bfloat16* __restrict__ wtb,
                                              __hip_bfloat16* __restrict__ u) {
    int wave = threadIdx.x >> 6;
    int lane = threadIdx.x & 63;
    int quad = lane >> 4;
    int l15  = lane & 15;
    int m0   = (blockIdx.x * 4 + wave) * 16;       // row tile base, < 16000

    const __hip_bfloat16* ap = afb + (m0 + l15) * KP + quad * 8;
    bf16x8_t a0 = *(const bf16x8_t*)(ap);
    bf16x8_t a1 = *(const bf16x8_t*)(ap + 32);
    bf16x8_t a2 = *(const bf16x8_t*)(ap + 64);
    bf16x8_t a3 = *(const bf16x8_t*)(ap + 96);

    int ntBeg = blockIdx.y * 7;
    int ntEnd = (blockIdx.y == 7) ? 57 : (ntBeg + 7);
    for (int nt = ntBeg; nt < ntEnd; ++nt) {
        int c = nt * 16 + l15;
        const __hip_bfloat16* bp = wtb + c * KP + quad * 8;
        bf16x8_t b0 = *(const bf16x8_t*)(bp);
        bf16x8_t b1 = *(const bf16x8_t*)(bp + 32);
        bf16x8_t b2 = *(const bf16x8_t*)(bp + 64);
        bf16x8_t b3 = *(const bf16x8_t*)(bp + 96);
        f32x4_t acc = {0.f, 0.f, 0.f, 0.f};
        acc = __builtin_amdgcn_mfma_f32_16x16x32_bf16(a0, b0, acc, 0, 0, 0);
        acc = __builtin_amdgcn_mfma_f32_16x16x32_bf16(a1, b1, acc, 0, 0, 0);
        acc = __builtin_amdgcn_mfma_f32_16x16x32_bf16(a2, b2, acc, 0, 0, 0);
        acc = __builtin_amdgcn_mfma_f32_16x16x32_bf16(a3, b3, acc, 0, 0, 0);
#pragma unroll
        for (int r = 0; r < 4; ++r) {
            int rr = m0 + quad * 4 + r;
            u[rr * SU + c] = __float2bfloat16(acc[r]);
        }
    }
}

// ---- bucket edges by DEST atom; pack (edge_id << 14) | src  (e<2^16, src<2^14)
__global__ __launch_bounds__(256) void hist_bucket(const int* __restrict__ a2p,
                                                   int* __restrict__ deg,
                                                   unsigned* __restrict__ bucket) {
    int e = blockIdx.x * 256 + threadIdx.x;
    if (e >= N_PAIRS) return;
    int dest = a2p[e * 2];
    int src  = a2p[e * 2 + 1];
    int slot = atomicAdd(&deg[dest], 1);
    if (slot < MAX_DEG)
        bucket[dest * MAX_DEG + slot] = ((unsigned)e << 14) | (unsigned)src;
}

// ---- accumulate: one wave per dest; two 32-lane halves process alternate
//      edges (4 cols/lane via ushort4), shfl-combine, coalesced float4 write.
//      Zero output atomics. Writes every row (deg==0 -> zeros), so no memset.
__global__ __launch_bounds__(256) void accum_kernel(const float* __restrict__ pf,
                                                    const __hip_bfloat16* __restrict__ u,
                                                    const int* __restrict__ deg,
                                                    const unsigned* __restrict__ bucket,
                                                    float* __restrict__ out) {
    int d    = blockIdx.x * 4 + (threadIdx.x >> 6);   // dest atom, < 16000
    int lane = threadIdx.x & 63;
    int h    = lane >> 5;                             // half 0/1
    int l    = lane & 31;                             // 0..31; active l<25
    bool act = (l < 25);                              // covers i = 4l .. 4l+3

    int n = deg[d];                                   // wave-uniform
    if (n > MAX_DEG) n = MAX_DEG;

    unsigned pk_l = 0;
    if (lane < n) pk_l = bucket[d * MAX_DEG + lane];  // coalesced preload

    float a0 = 0.f, a1 = 0.f, a2 = 0.f, a3 = 0.f;
    for (int t = h; t < n; t += 2) {                  // halves take alternate edges
        unsigned pk = (unsigned)__shfl((int)pk_l, t, 64);
        int e   = (int)(pk >> 14);
        int src = (int)(pk & 16383u);
        const float* pfe = pf + e * N_FEAT;
        float4 p0 = *(const float4*)(pfe);            // uniform -> broadcast
        float4 p1 = *(const float4*)(pfe + 4);
        if (act) {
            const unsigned short* ur = (const unsigned short*)(u + (size_t)src * SU);
            ushort4 bb = *(const ushort4*)(ur + N_FEAT * N_HIDDEN + 4 * l);
            a0 += __uint_as_float((unsigned)bb.x << 16);
            a1 += __uint_as_float((unsigned)bb.y << 16);
            a2 += __uint_as_float((unsigned)bb.z << 16);
            a3 += __uint_as_float((unsigned)bb.w << 16);
            float pv[8] = {p0.x, p0.y, p0.z, p0.w, p1.x, p1.y, p1.z, p1.w};
#pragma unroll
            for (int f = 0; f < N_FEAT; ++f) {
                ushort4 uu = *(const ushort4*)(ur + f * N_HIDDEN + 4 * l);
                a0 += pv[f] * __uint_as_float((unsigned)uu.x << 16);
                a1 += pv[f] * __uint_as_float((unsigned)uu.y << 16);
                a2 += pv[f] * __uint_as_float((unsigned)uu.z << 16);
                a3 += pv[f] * __uint_as_float((unsigned)uu.w << 16);
            }
        }
    }
    // combine: half-0 lane l reads half-1 lane l+32 (h==1 lanes read themselves)
    a0 += __shfl(a0, l + 32, 64);
    a1 += __shfl(a1, l + 32, 64);
    a2 += __shfl(a2, l + 32, 64);
    a3 += __shfl(a3, l + 32, 64);
    if (h == 0 && act) {
        float4 o = {a0, a1, a2, a3};
        *(float4*)(out + d * N_HIDDEN + 4 * l) = o;   // coalesced, covers all rows
    }
}

extern "C" void kernel_launch(void* const* d_in, const int* in_sizes, int n_in,
                              void* d_out, int out_size, void* d_ws, size_t ws_size,
                              hipStream_t stream) {
    const float* pf  = (const float*)d_in[0];   // (64000, 8)
    const float* af  = (const float*)d_in[1];   // (16000, 100)
    const int*   a2p = (const int*)d_in[2];     // (64000, 2)
    const float* W   = (const float*)d_in[3];   // (8, 10000)
    const float* b   = (const float*)d_in[4];   // (10000,)
    float* out = (float*)d_out;                 // (16000, 100) fp32

    char* ws = (char*)d_ws;
    __hip_bfloat16* afb = (__hip_bfloat16*)ws;                        // 4,096,000 B
    __hip_bfloat16* wtb = (__hip_bfloat16*)(ws + 4096000);            //   233,472 B
    __hip_bfloat16* u   = (__hip_bfloat16*)(ws + 4096000 + 233472);   // 29,184,000 B
    int* deg         = (int*)(ws + 4096000 + 233472 + 29184000);      //    64,000 B
    unsigned* bucket = (unsigned*)(ws + 4096000 + 233472 + 29184000 + 64000); // 4,096,000 B

    hipMemsetAsync(deg, 0, N_ATOMS * sizeof(int), stream);
    setup_kernel<<<(N1_SETUP + N2_SETUP) / 256, 256, 0, stream>>>(af, W, b, afb, wtb);
    hist_bucket<<<(N_PAIRS + 255) / 256, 256, 0, stream>>>(a2p, deg, bucket);
    gemm_u<<<dim3(250, 8), 256, 0, stream>>>(afb, wtb, u);
    accum_kernel<<<N_ATOMS / 4, 256, 0, stream>>>(pf, u, deg, bucket, out);
}

// Round 5
// 125.818 us; speedup vs baseline: 1.3506x; 1.0623x over previous
//
#include <hip/hip_runtime.h>
#include <hip/hip_bf16.h>

// Problem constants
#define N_PAIRS   64000
#define N_ATOMS   16000
#define N_FEAT    8
#define N_HIDDEN  100
// Aggregate-first formulation:
//   S[d, f*100+j] = sum_{e: dest(e)=d} pf[e,f] * AF[src_e, j]   (f<8)
//   S[d, 800+j]   = sum_{e: dest(e)=d} AF[src_e, j]             (bias block)
//   out[d,i]      = sum_k S[d,k] * Wbig[k,i],  Wbig[f*100+j,i]=W[f,i*100+j],
//                   Wbig[800+j,i]=b[i*100+j]
#define SK        928     // S row stride (bf16): 29 MFMA k-steps of 32
#define SW        1024    // Wbig row stride (stored transposed: wtb2[i][k])
#define MAX_DEG   64      // bucket capacity per dest (Poisson(4): P(>=64) ~ 1e-56)

typedef __attribute__((ext_vector_type(8))) short bf16x8_t;   // 8 bf16 = 4 VGPRs
typedef __attribute__((ext_vector_type(4))) float f32x4_t;

// ---- setup: wtb2[i][k] = Wbig[k][i] in bf16 (112 x 1024, zero-padded);
//      also zero-inits deg[] (folded in)
__global__ __launch_bounds__(256) void setup_kernel(const float* __restrict__ W,
                                                    const float* __restrict__ b,
                                                    __hip_bfloat16* __restrict__ wtb2,
                                                    int* __restrict__ deg) {
    int id = blockIdx.x * 256 + threadIdx.x;   // < 112*1024 = 114688
    if (id < N_ATOMS) deg[id] = 0;
    int i = id >> 10;                          // 0..111 (output col)
    int k = id & 1023;                         // 0..1023 (contraction index)
    float v = 0.f;
    if (i < N_HIDDEN) {
        if (k < 800) {
            int f = k / N_HIDDEN;
            int j = k - f * N_HIDDEN;
            v = W[f * (N_HIDDEN * N_HIDDEN) + i * N_HIDDEN + j];
        } else if (k < 900) {
            int j = k - 800;
            v = b[i * N_HIDDEN + j];
        }
    }
    wtb2[id] = __float2bfloat16(v);
}

// ---- bucket edges by DEST atom; pack (edge_id << 14) | src  (e<2^16, src<2^14)
__global__ __launch_bounds__(256) void hist_bucket(const int* __restrict__ a2p,
                                                   int* __restrict__ deg,
                                                   unsigned* __restrict__ bucket) {
    int e = blockIdx.x * 256 + threadIdx.x;    // grid exactly covers N_PAIRS
    int dest = a2p[e * 2];
    int src  = a2p[e * 2 + 1];
    int slot = atomicAdd(&deg[dest], 1);
    if (slot < MAX_DEG)
        bucket[dest * MAX_DEG + slot] = ((unsigned)e << 14) | (unsigned)src;
}

// ---- edge_s: one wave per dest. Gather AF rows (fp32, cache-resident),
//      accumulate 9 pf-weighted copies in registers, write S row coalesced.
//      Lanes 0..49 own cols {2l,2l+1}; lanes 50..63 zero the K-pad (900..927).
__global__ __launch_bounds__(256) void edge_s(const float* __restrict__ pf,
                                              const float* __restrict__ af,
                                              const int* __restrict__ deg,
                                              const unsigned* __restrict__ bucket,
                                              __hip_bfloat16* __restrict__ S) {
    int d    = blockIdx.x * 4 + (threadIdx.x >> 6);   // dest atom, < 16000
    int lane = threadIdx.x & 63;
    bool act = (lane < 50);

    int n = deg[d];                                   // wave-uniform
    if (n > MAX_DEG) n = MAX_DEG;

    unsigned pk_l = 0;
    if (lane < n) pk_l = bucket[d * MAX_DEG + lane];  // coalesced preload

    float acc[9][2] = {};                             // f=0..7 weighted, f=8 bias
    for (int t = 0; t < n; ++t) {
        unsigned pk = (unsigned)__shfl((int)pk_l, t, 64);
        int e   = (int)(pk >> 14);
        int src = (int)(pk & 16383u);
        const float* pfe = pf + e * N_FEAT;
        float4 p0 = *(const float4*)(pfe);            // uniform -> broadcast
        float4 p1 = *(const float4*)(pfe + 4);
        if (act) {
            float2 a = *(const float2*)(af + src * N_HIDDEN + 2 * lane);
            float pv[8] = {p0.x, p0.y, p0.z, p0.w, p1.x, p1.y, p1.z, p1.w};
#pragma unroll
            for (int f = 0; f < N_FEAT; ++f) {
                acc[f][0] += pv[f] * a.x;
                acc[f][1] += pv[f] * a.y;
            }
            acc[8][0] += a.x;
            acc[8][1] += a.y;
        }
    }
    __hip_bfloat16* srow = S + (size_t)d * SK;
    if (act) {
#pragma unroll
        for (int f = 0; f < 9; ++f) {
            __hip_bfloat162 h;
            h.x = __float2bfloat16(acc[f][0]);
            h.y = __float2bfloat16(acc[f][1]);
            *(__hip_bfloat162*)(srow + f * N_HIDDEN + 2 * lane) = h;
        }
    } else {
        __hip_bfloat162 z;
        z.x = __float2bfloat16(0.f);
        z.y = z.x;
        *(__hip_bfloat162*)(srow + 900 + 2 * (lane - 50)) = z;   // cols 900..927
    }
}

// ---- gemm_out: out(16000x100 fp32) = S(16000x928 bf16) @ wtb2^T
//      grid (250, 7): wave = one 16-row m-tile at n-tile blockIdx.y; 29 k-steps
__global__ __launch_bounds__(256) void gemm_out(const __hip_bfloat16* __restrict__ S,
                                                const __hip_bfloat16* __restrict__ wtb2,
                                                float* __restrict__ out) {
    int wave = threadIdx.x >> 6;
    int lane = threadIdx.x & 63;
    int quad = lane >> 4;
    int l15  = lane & 15;
    int m0   = (blockIdx.x * 4 + wave) * 16;   // < 16000
    int n0   = blockIdx.y * 16;                // 0,16,...,96

    const __hip_bfloat16* ap = S    + (size_t)(m0 + l15) * SK + quad * 8;
    const __hip_bfloat16* bp = wtb2 + (size_t)(n0 + l15) * SW + quad * 8;

    f32x4_t acc = {0.f, 0.f, 0.f, 0.f};
    for (int k = 0; k < 29; ++k) {
        bf16x8_t a  = *(const bf16x8_t*)(ap + k * 32);
        bf16x8_t bb = *(const bf16x8_t*)(bp + k * 32);
        acc = __builtin_amdgcn_mfma_f32_16x16x32_bf16(a, bb, acc, 0, 0, 0);
    }
    int c = n0 + l15;
    if (c < N_HIDDEN) {                        // n-tile 6 covers cols 96..111
#pragma unroll
        for (int r = 0; r < 4; ++r)
            out[(size_t)(m0 + quad * 4 + r) * N_HIDDEN + c] = acc[r];
    }
}

extern "C" void kernel_launch(void* const* d_in, const int* in_sizes, int n_in,
                              void* d_out, int out_size, void* d_ws, size_t ws_size,
                              hipStream_t stream) {
    const float* pf  = (const float*)d_in[0];   // (64000, 8)
    const float* af  = (const float*)d_in[1];   // (16000, 100)
    const int*   a2p = (const int*)d_in[2];     // (64000, 2)
    const float* W   = (const float*)d_in[3];   // (8, 10000)
    const float* b   = (const float*)d_in[4];   // (10000,)
    float* out = (float*)d_out;                 // (16000, 100) fp32

    char* ws = (char*)d_ws;
    __hip_bfloat16* wtb2 = (__hip_bfloat16*)ws;                      // 112*1024*2 =   229,376 B
    __hip_bfloat16* S    = (__hip_bfloat16*)(ws + 229376);           // 16000*928*2 = 29,696,000 B
    int* deg             = (int*)(ws + 229376 + 29696000);           //     64,000 B
    unsigned* bucket     = (unsigned*)(ws + 229376 + 29696000 + 64000); // 4,096,000 B

    setup_kernel<<<(112 * 1024) / 256, 256, 0, stream>>>(W, b, wtb2, deg);
    hist_bucket<<<N_PAIRS / 256, 256, 0, stream>>>(a2p, deg, bucket);
    edge_s<<<N_ATOMS / 4, 256, 0, stream>>>(pf, af, deg, bucket, S);
    gemm_out<<<dim3(250, 7), 256, 0, stream>>>(S, wtb2, out);
}